// Round 3
// baseline (7079.275 us; speedup 1.0000x reference)
//
#include <hip/hip_runtime.h>

#define DD 128

typedef __attribute__((ext_vector_type(8))) short bf16x8;
typedef __attribute__((ext_vector_type(4))) short bf16x4;
typedef __attribute__((ext_vector_type(4))) float f32x4;

__device__ __forceinline__ unsigned short f2bf(float f) {
  union { float f; unsigned u; } v; v.f = f;
  unsigned u = v.u;
  return (unsigned short)((u + 0x7FFFu + ((u >> 16) & 1u)) >> 16);
}

__device__ __forceinline__ bf16x8 pack8(f32x4 a, f32x4 b) {
  bf16x8 r;
  r[0] = (short)f2bf(a.x); r[1] = (short)f2bf(a.y);
  r[2] = (short)f2bf(a.z); r[3] = (short)f2bf(a.w);
  r[4] = (short)f2bf(b.x); r[5] = (short)f2bf(b.y);
  r[6] = (short)f2bf(b.z); r[7] = (short)f2bf(b.w);
  return r;
}

// edge_index may arrive as int32 or int64. int64 viewed as int32 has zero
// high words; values in [0,50000) make 4 consecutive zeros ~impossible for
// genuine int32 data.
__device__ __forceinline__ bool idx_is64(const int* p) {
  return (p[1] | p[3] | p[5] | p[7]) == 0;
}
__device__ __forceinline__ int ld_idx(const int* p, long long i, bool is64) {
  return is64 ? (int)((const long long*)p)[i] : p[i];
}

__global__ void k_count(const int* __restrict__ idx, int* __restrict__ cnt, int E) {
  int e = blockIdx.x * blockDim.x + threadIdx.x;
  if (e >= E) return;
  bool is64 = idx_is64(idx);
  int d = ld_idx(idx, (long long)E + e, is64);
  atomicAdd(&cnt[d], 1);
}

// Fused per-16-edge-tile kernel:
//  1) rel GEMM: ea_out = ea_in @ W_rel^T + b_rel   (bf16 MFMA, W in swizzled LDS)
//  2) message scatter: aggsum[dst_e] += x[src_e] * ea_in[e]   (f32 HW atomics)
__global__ __launch_bounds__(256) void k_edge(const float* __restrict__ ea_in,
    float* __restrict__ ea_out, const float* __restrict__ x,
    float* __restrict__ aggsum, const int* __restrict__ idx,
    const float* __restrict__ W, const float* __restrict__ bias,
    int ntiles, int E) {
  __shared__ short Wl[DD * DD];
  for (int q = threadIdx.x; q < DD * DD / 4; q += 256) {
    int off = q * 4;
    int f = off >> 7, d = off & 127;
    f32x4 w = *(const f32x4*)(W + off);
    unsigned byte = ((unsigned)(f * 256 + d * 2)) ^ (unsigned)((f & 7) << 4);
    bf16x4 s4;
    s4[0] = (short)f2bf(w.x); s4[1] = (short)f2bf(w.y);
    s4[2] = (short)f2bf(w.z); s4[3] = (short)f2bf(w.w);
    *(bf16x4*)((char*)Wl + byte) = s4;
  }
  __syncthreads();
  bool is64 = idx_is64(idx);
  int wave = threadIdx.x >> 6, lane = threadIdx.x & 63;
  int r = lane & 15, g = lane >> 4;
  for (int tile = blockIdx.x * 4 + wave; tile < ntiles; tile += gridDim.x * 4) {
    int e0 = tile * 16;
    const float* rowp = ea_in + (size_t)(e0 + r) * DD;
    f32x4 av[8];
    bf16x8 a[4];
#pragma unroll
    for (int ks = 0; ks < 4; ++ks) {
      const float* p = rowp + ks * 32 + g * 8;
      av[2 * ks]     = *(const f32x4*)p;
      av[2 * ks + 1] = *(const f32x4*)(p + 4);
      a[ks] = pack8(av[2 * ks], av[2 * ks + 1]);
    }
    // ---- message scatter (uses f32 ea values while GEMM runs) ----
    int se = ld_idx(idx, e0 + r, is64);
    int de = ld_idx(idx, (long long)E + e0 + r, is64);
    const float* xrow = x + (size_t)se * DD;
    float* arow = aggsum + (size_t)de * DD;
    // ---- rel GEMM ----
    f32x4 acc[8];
#pragma unroll
    for (int ct = 0; ct < 8; ++ct) acc[ct] = (f32x4){0.f, 0.f, 0.f, 0.f};
#pragma unroll
    for (int ct = 0; ct < 8; ++ct) {
      int f = ct * 16 + r;
      unsigned base = (unsigned)(f * 256);
      unsigned sw = (unsigned)((f & 7) << 4);
#pragma unroll
      for (int ks = 0; ks < 4; ++ks) {
        unsigned byte = (base + (unsigned)(ks * 64 + g * 16)) ^ sw;
        bf16x8 b = *(const bf16x8*)((const char*)Wl + byte);
        acc[ct] = __builtin_amdgcn_mfma_f32_16x16x32_bf16(a[ks], b, acc[ct], 0, 0, 0);
      }
    }
#pragma unroll
    for (int ks = 0; ks < 4; ++ks) {
      int c0 = ks * 32 + g * 8;
      f32x4 x0 = *(const f32x4*)(xrow + c0);
      f32x4 x1 = *(const f32x4*)(xrow + c0 + 4);
      f32x4 m0 = x0 * av[2 * ks];
      f32x4 m1 = x1 * av[2 * ks + 1];
#pragma unroll
      for (int j = 0; j < 4; ++j) unsafeAtomicAdd(arow + c0 + j, m0[j]);
#pragma unroll
      for (int j = 0; j < 4; ++j) unsafeAtomicAdd(arow + c0 + 4 + j, m1[j]);
    }
    // ---- store ea_out ----
    float* ob = ea_out + (size_t)e0 * DD;
#pragma unroll
    for (int ct = 0; ct < 8; ++ct) {
      int col = ct * 16 + r;
      float bv = bias[col];
#pragma unroll
      for (int j = 0; j < 4; ++j) {
        ob[(size_t)(g * 4 + j) * DD + col] = acc[ct][j] + bv;
      }
    }
  }
}

// xn = (aggsum*invdeg) @ W_in^T + x @ W_self^T + b_self + (deg>0)*b_in ; BN stats
__global__ __launch_bounds__(256) void k_node(const float* __restrict__ aggsum,
    const float* __restrict__ xc, const float* __restrict__ W_in,
    const float* __restrict__ W_self, const float* __restrict__ b_in,
    const float* __restrict__ b_self, const int* __restrict__ cnt,
    float* __restrict__ xn, float* __restrict__ gsum, float* __restrict__ gssq,
    int do_stats, int ntiles) {
  __shared__ short Wl[DD * 256];   // [f][k] k<128:W_in, k>=128:W_self (bf16, swizzled)
  for (int q = threadIdx.x; q < DD * 256 / 4; q += 256) {
    int off = q * 4;
    int f = off >> 8, k = off & 255;
    f32x4 w = (k < 128) ? *(const f32x4*)(W_in + f * 128 + k)
                        : *(const f32x4*)(W_self + f * 128 + (k - 128));
    unsigned byte = ((unsigned)(f * 512 + k * 2)) ^ (unsigned)((f & 7) << 4);
    bf16x4 s4;
    s4[0] = (short)f2bf(w.x); s4[1] = (short)f2bf(w.y);
    s4[2] = (short)f2bf(w.z); s4[3] = (short)f2bf(w.w);
    *(bf16x4*)((char*)Wl + byte) = s4;
  }
  __syncthreads();
  int wave = threadIdx.x >> 6, lane = threadIdx.x & 63;
  int tile = blockIdx.x * 4 + wave;
  if (tile >= ntiles) return;
  int r = lane & 15, g = lane >> 4;
  int arowi = tile * 16 + r;
  const float* arow = aggsum + (size_t)arowi * DD;
  const float* xrow = xc + (size_t)arowi * DD;
  int dr = cnt[arowi];
  float inv = (dr > 0) ? 1.0f / (float)dr : 0.0f;
  bf16x8 a[8];
#pragma unroll
  for (int ks = 0; ks < 8; ++ks) {
    if (ks < 4) {
      const float* p = arow + ks * 32 + g * 8;
      f32x4 v0 = *(const f32x4*)p * inv;
      f32x4 v1 = *(const f32x4*)(p + 4) * inv;
      a[ks] = pack8(v0, v1);
    } else {
      const float* p = xrow + (ks - 4) * 32 + g * 8;
      a[ks] = pack8(*(const f32x4*)p, *(const f32x4*)(p + 4));
    }
  }
  f32x4 acc[8];
#pragma unroll
  for (int ct = 0; ct < 8; ++ct) acc[ct] = (f32x4){0.f, 0.f, 0.f, 0.f};
#pragma unroll
  for (int ct = 0; ct < 8; ++ct) {
    int f = ct * 16 + r;
    unsigned base = (unsigned)(f * 512);
    unsigned sw = (unsigned)((f & 7) << 4);
#pragma unroll
    for (int ks = 0; ks < 8; ++ks) {
      unsigned byte = (base + (unsigned)(ks * 64 + g * 16)) ^ sw;
      bf16x8 b = *(const bf16x8*)((const char*)Wl + byte);
      acc[ct] = __builtin_amdgcn_mfma_f32_16x16x32_bf16(a[ks], b, acc[ct], 0, 0, 0);
    }
  }
  int nbase = tile * 16;
  float degmask[4];
#pragma unroll
  for (int j = 0; j < 4; ++j)
    degmask[j] = (cnt[nbase + g * 4 + j] > 0) ? 1.0f : 0.0f;
#pragma unroll
  for (int ct = 0; ct < 8; ++ct) {
    int col = ct * 16 + r;
    float bi = b_in[col], bs = b_self[col];
    float s = 0.f, s2 = 0.f;
#pragma unroll
    for (int j = 0; j < 4; ++j) {
      float v = acc[ct][j] + bs + bi * degmask[j];
      xn[(size_t)(nbase + g * 4 + j) * DD + col] = v;
      s += v; s2 += v * v;
    }
    if (do_stats) {
      s += __shfl_xor(s, 16);  s += __shfl_xor(s, 32);
      s2 += __shfl_xor(s2, 16); s2 += __shfl_xor(s2, 32);
      if (g == 0) { atomicAdd(&gsum[col], s); atomicAdd(&gssq[col], s2); }
    }
  }
}

__global__ void k_bnfin(const float* __restrict__ gsum, const float* __restrict__ gssq,
    const float* __restrict__ gamma, const float* __restrict__ beta,
    float* __restrict__ scale, float* __restrict__ shift, int N) {
  int d = threadIdx.x;
  float mu = gsum[d] / (float)N;
  float var = gssq[d] / (float)N - mu * mu;
  float rs = rsqrtf(var + 1e-5f);
  float sc = rs * gamma[d];
  scale[d] = sc;
  shift[d] = beta[d] - mu * sc;
}

__global__ void k_bnrelu(float* __restrict__ x, const float* __restrict__ scale,
                         const float* __restrict__ shift, int total4) {
  int i = blockIdx.x * blockDim.x + threadIdx.x;
  if (i >= total4) return;
  f32x4 v = ((f32x4*)x)[i];
  int d0 = (i * 4) & 127;
  v.x = fmaxf(v.x * scale[d0] + shift[d0], 0.f);
  v.y = fmaxf(v.y * scale[d0 + 1] + shift[d0 + 1], 0.f);
  v.z = fmaxf(v.z * scale[d0 + 2] + shift[d0 + 2], 0.f);
  v.w = fmaxf(v.w * scale[d0 + 3] + shift[d0 + 3], 0.f);
  ((f32x4*)x)[i] = v;
}

static inline size_t alignup(size_t v, size_t a) { return (v + a - 1) & ~(a - 1); }

extern "C" void kernel_launch(void* const* d_in, const int* in_sizes, int n_in,
                              void* d_out, int out_size, void* d_ws, size_t ws_size,
                              hipStream_t stream) {
  const float* x0     = (const float*)d_in[0];
  const float* ea0    = (const float*)d_in[1];
  const float* w_self = (const float*)d_in[2];
  const float* b_self = (const float*)d_in[3];
  const float* w_in   = (const float*)d_in[4];
  const float* b_in   = (const float*)d_in[5];
  const float* w_rel  = (const float*)d_in[6];
  const float* b_rel  = (const float*)d_in[7];
  const float* gamma  = (const float*)d_in[8];
  const float* beta   = (const float*)d_in[9];
  const int*   idx    = (const int*)d_in[10];

  const int N = in_sizes[0] / DD;
  const int E = in_sizes[1] / DD;

  char* w = (char*)d_ws;
  size_t off = 0;
  int* cnt       = (int*)(w + off); off = alignup(off + (size_t)N * 4, 256);
  float* gsum    = (float*)(w + off); off = alignup(off + 128 * 4, 256);
  float* gssq    = (float*)(w + off); off = alignup(off + 128 * 4, 256);
  float* scale   = (float*)(w + off); off = alignup(off + 128 * 4, 256);
  float* shift   = (float*)(w + off); off = alignup(off + 128 * 4, 256);
  float* aggsum  = (float*)(w + off); off = alignup(off + (size_t)N * DD * 4, 256);
  float* xbufB   = (float*)(w + off); off = alignup(off + (size_t)N * DD * 4, 256);
  (void)ws_size; (void)n_in; (void)out_size;

  float* out_x  = (float*)d_out;
  float* out_ea = out_x + (size_t)N * DD;

  // ---- degree counts (depends only on edge_index) ----
  (void)hipMemsetAsync(cnt, 0, (size_t)N * 4, stream);
  int ethreads = 256, eblocks = (E + ethreads - 1) / ethreads;
  k_count<<<eblocks, ethreads, 0, stream>>>(idx, cnt, E);

  const int ntN = N / 16;           // 3125
  const int ntE = E / 16;           // 40000
  const int nodeBlocks = (ntN + 3) / 4;
  const int edgeBlocks = 2048;

  const float* xc = x0;
  const float* eac = ea0;

  for (int i = 0; i < 3; ++i) {
    float* xn  = (i == 0) ? out_x : (i == 1) ? xbufB : out_x;
    float* ean = out_ea;            // layer0: ea0 -> out_ea; then in-place
    int do_stats = (i < 2) ? 1 : 0;

    (void)hipMemsetAsync(aggsum, 0, (size_t)N * DD * 4, stream);
    if (do_stats) {
      (void)hipMemsetAsync(gsum, 0, 128 * 4, stream);
      (void)hipMemsetAsync(gssq, 0, 128 * 4, stream);
    }
    k_edge<<<edgeBlocks, 256, 0, stream>>>(eac, ean, xc, aggsum, idx,
        w_rel + (size_t)i * DD * DD, b_rel + (size_t)i * DD, ntE, E);
    k_node<<<nodeBlocks, 256, 0, stream>>>(aggsum, xc,
        w_in + (size_t)i * DD * DD, w_self + (size_t)i * DD * DD,
        b_in + (size_t)i * DD, b_self + (size_t)i * DD,
        cnt, xn, gsum, gssq, do_stats, ntN);
    if (do_stats) {
      k_bnfin<<<1, 128, 0, stream>>>(gsum, gssq, gamma + (size_t)i * DD,
                                     beta + (size_t)i * DD, scale, shift, N);
      k_bnrelu<<<((size_t)N * DD / 4 + 255) / 256, 256, 0, stream>>>(
          xn, scale, shift, N * DD / 4);
    }
    xc = xn;
    eac = ean;
  }
}

// Round 4
// 1155.385 us; speedup vs baseline: 6.1272x; 6.1272x over previous
//
#include <hip/hip_runtime.h>

#define DD 128

typedef __attribute__((ext_vector_type(8))) short bf16x8;
typedef __attribute__((ext_vector_type(4))) short bf16x4;
typedef __attribute__((ext_vector_type(4))) float f32x4;
typedef unsigned short u16;

__device__ __forceinline__ unsigned short f2bf(float f) {
  union { float f; unsigned u; } v; v.f = f;
  unsigned u = v.u;
  return (unsigned short)((u + 0x7FFFu + ((u >> 16) & 1u)) >> 16);
}

__device__ __forceinline__ bf16x8 pack8(f32x4 a, f32x4 b) {
  bf16x8 r;
  r[0] = (short)f2bf(a.x); r[1] = (short)f2bf(a.y);
  r[2] = (short)f2bf(a.z); r[3] = (short)f2bf(a.w);
  r[4] = (short)f2bf(b.x); r[5] = (short)f2bf(b.y);
  r[6] = (short)f2bf(b.z); r[7] = (short)f2bf(b.w);
  return r;
}

__device__ __forceinline__ float ldv(const float* p) { return *p; }
__device__ __forceinline__ float ldv(const u16* p) {
  union { unsigned u; float f; } v; v.u = ((unsigned)*p) << 16; return v.f;
}
__device__ __forceinline__ bf16x8 load_frag(const float* p) {
  return pack8(*(const f32x4*)p, *(const f32x4*)(p + 4));
}
__device__ __forceinline__ bf16x8 load_frag(const u16* p) {
  return *(const bf16x8*)p;
}
__device__ __forceinline__ void stv(float* p, float v) { *p = v; }
__device__ __forceinline__ void stv(u16* p, float v) { *p = f2bf(v); }

// edge_index may arrive as int32 or int64. int64 viewed as int32 has zero
// high words; values in [0,50000) make 4 consecutive zeros ~impossible for
// genuine int32 data.
__device__ __forceinline__ bool idx_is64(const int* p) {
  return (p[1] | p[3] | p[5] | p[7]) == 0;
}
__device__ __forceinline__ int ld_idx(const int* p, long long i, bool is64) {
  return is64 ? (int)((const long long*)p)[i] : p[i];
}

__global__ void k_count(const int* __restrict__ idx, int* __restrict__ cnt, int E) {
  int e = blockIdx.x * blockDim.x + threadIdx.x;
  if (e >= E) return;
  bool is64 = idx_is64(idx);
  int d = ld_idx(idx, (long long)E + e, is64);
  atomicAdd(&cnt[d], 1);
}

__global__ __launch_bounds__(1024) void k_scan(const int* __restrict__ cnt,
    int* __restrict__ row_start, int* __restrict__ cursor, int N) {
  __shared__ int part[1024];
  int t = threadIdx.x;
  int chunk = (N + 1023) >> 10;
  int lo = t * chunk, hi = lo + chunk; if (hi > N) hi = N; if (lo > N) lo = N;
  int s = 0;
  for (int i = lo; i < hi; ++i) s += cnt[i];
  part[t] = s;
  __syncthreads();
  for (int off = 1; off < 1024; off <<= 1) {
    int v = (t >= off) ? part[t - off] : 0;
    __syncthreads();
    part[t] += v;
    __syncthreads();
  }
  int run = (t == 0) ? 0 : part[t - 1];
  for (int i = lo; i < hi; ++i) {
    row_start[i] = run; cursor[i] = run; run += cnt[i];
  }
  if (t == 1023) row_start[N] = part[1023];
}

__global__ void k_fill(const int* __restrict__ idx, int* __restrict__ cursor,
                       int* __restrict__ edge_of, int E) {
  int e = blockIdx.x * blockDim.x + threadIdx.x;
  if (e >= E) return;
  bool is64 = idx_is64(idx);
  int d = ld_idx(idx, (long long)E + e, is64);
  int pos = atomicAdd(&cursor[d], 1);
  edge_of[pos] = e;
}

// segment-mean of x[src] * ea over edges of each node. block = node.
// 2-deep software pipeline on the gather chain.
template <typename T>
__global__ __launch_bounds__(128) void k_agg(const T* __restrict__ x,
    const T* __restrict__ ea, const int* __restrict__ idx,
    const int* __restrict__ row_start, const int* __restrict__ edge_of,
    float* __restrict__ aggm) {
  int n = blockIdx.x;
  int d = threadIdx.x;
  bool is64 = idx_is64(idx);
  int s0 = row_start[n], s1 = row_start[n + 1];
  int len = s1 - s0;
  float s = 0.f;
  for (int kk = 0; kk < len; kk += 2) {
    int e0 = edge_of[s0 + kk];
    bool has1 = (kk + 1 < len);
    int e1 = has1 ? edge_of[s0 + kk + 1] : e0;
    int a0 = ld_idx(idx, e0, is64);
    int a1 = ld_idx(idx, e1, is64);
    float xv0 = ldv(x + (size_t)a0 * DD + d);
    float ev0 = ldv(ea + (size_t)e0 * DD + d);
    float xv1 = ldv(x + (size_t)a1 * DD + d);
    float ev1 = ldv(ea + (size_t)e1 * DD + d);
    s += xv0 * ev0;
    s = has1 ? (s + xv1 * ev1) : s;
  }
  float inv = (len > 0) ? 1.0f / (float)len : 0.0f;
  aggm[(size_t)n * DD + d] = s * inv;
}

// ea_out[e][f] = sum_d ea_in[e][d] * W[f][d] + bias[f]  (in-place safe per-row)
template <typename TI, typename TO>
__global__ __launch_bounds__(256) void k_rel(const TI* __restrict__ ea_in,
    TO* __restrict__ ea_out, const float* __restrict__ W,
    const float* __restrict__ bias, int ntiles) {
  __shared__ short Wl[DD * DD];
  for (int q = threadIdx.x; q < DD * DD / 4; q += 256) {
    int off = q * 4;
    int f = off >> 7, d = off & 127;
    f32x4 w = *(const f32x4*)(W + off);
    unsigned byte = ((unsigned)(f * 256 + d * 2)) ^ (unsigned)((f & 7) << 4);
    bf16x4 s4;
    s4[0] = (short)f2bf(w.x); s4[1] = (short)f2bf(w.y);
    s4[2] = (short)f2bf(w.z); s4[3] = (short)f2bf(w.w);
    *(bf16x4*)((char*)Wl + byte) = s4;
  }
  __syncthreads();
  int wave = threadIdx.x >> 6, lane = threadIdx.x & 63;
  int r = lane & 15, g = lane >> 4;
  for (int tile = blockIdx.x * 4 + wave; tile < ntiles; tile += gridDim.x * 4) {
    const TI* rowp = ea_in + (size_t)(tile * 16 + r) * DD;
    bf16x8 a[4];
#pragma unroll
    for (int ks = 0; ks < 4; ++ks) a[ks] = load_frag(rowp + ks * 32 + g * 8);
    f32x4 acc[8];
#pragma unroll
    for (int ct = 0; ct < 8; ++ct) acc[ct] = (f32x4){0.f, 0.f, 0.f, 0.f};
#pragma unroll
    for (int ct = 0; ct < 8; ++ct) {
      int f = ct * 16 + r;
      unsigned base = (unsigned)(f * 256);
      unsigned sw = (unsigned)((f & 7) << 4);
#pragma unroll
      for (int ks = 0; ks < 4; ++ks) {
        unsigned byte = (base + (unsigned)(ks * 64 + g * 16)) ^ sw;
        bf16x8 b = *(const bf16x8*)((const char*)Wl + byte);
        acc[ct] = __builtin_amdgcn_mfma_f32_16x16x32_bf16(a[ks], b, acc[ct], 0, 0, 0);
      }
    }
    TO* ob = ea_out + (size_t)tile * 16 * DD;
#pragma unroll
    for (int ct = 0; ct < 8; ++ct) {
      int col = ct * 16 + r;
      float bv = bias[col];
#pragma unroll
      for (int j = 0; j < 4; ++j) {
        stv(ob + (size_t)(g * 4 + j) * DD + col, acc[ct][j] + bv);
      }
    }
  }
}

// xn = aggm @ W_in^T + x @ W_self^T + b_self + (deg>0)*b_in ; optional BN stats
template <typename T>
__global__ __launch_bounds__(256) void k_node(const float* __restrict__ aggm,
    const T* __restrict__ xc, const float* __restrict__ W_in,
    const float* __restrict__ W_self, const float* __restrict__ b_in,
    const float* __restrict__ b_self, const int* __restrict__ cnt,
    float* __restrict__ xn, float* __restrict__ gsum, float* __restrict__ gssq,
    int do_stats, int ntiles) {
  __shared__ short Wl[DD * 256];   // [f][k] k<128:W_in, k>=128:W_self (bf16, swizzled)
  for (int q = threadIdx.x; q < DD * 256 / 4; q += 256) {
    int off = q * 4;
    int f = off >> 8, k = off & 255;
    f32x4 w = (k < 128) ? *(const f32x4*)(W_in + f * 128 + k)
                        : *(const f32x4*)(W_self + f * 128 + (k - 128));
    unsigned byte = ((unsigned)(f * 512 + k * 2)) ^ (unsigned)((f & 7) << 4);
    bf16x4 s4;
    s4[0] = (short)f2bf(w.x); s4[1] = (short)f2bf(w.y);
    s4[2] = (short)f2bf(w.z); s4[3] = (short)f2bf(w.w);
    *(bf16x4*)((char*)Wl + byte) = s4;
  }
  __syncthreads();
  int wave = threadIdx.x >> 6, lane = threadIdx.x & 63;
  int tile = blockIdx.x * 4 + wave;
  if (tile >= ntiles) return;
  int r = lane & 15, g = lane >> 4;
  int arowi = tile * 16 + r;
  const float* arow = aggm + (size_t)arowi * DD;
  const T* xrow = xc + (size_t)arowi * DD;
  bf16x8 a[8];
#pragma unroll
  for (int ks = 0; ks < 8; ++ks) {
    if (ks < 4) a[ks] = load_frag(arow + ks * 32 + g * 8);
    else        a[ks] = load_frag(xrow + (ks - 4) * 32 + g * 8);
  }
  f32x4 acc[8];
#pragma unroll
  for (int ct = 0; ct < 8; ++ct) acc[ct] = (f32x4){0.f, 0.f, 0.f, 0.f};
#pragma unroll
  for (int ct = 0; ct < 8; ++ct) {
    int f = ct * 16 + r;
    unsigned base = (unsigned)(f * 512);
    unsigned sw = (unsigned)((f & 7) << 4);
#pragma unroll
    for (int ks = 0; ks < 8; ++ks) {
      unsigned byte = (base + (unsigned)(ks * 64 + g * 16)) ^ sw;
      bf16x8 b = *(const bf16x8*)((const char*)Wl + byte);
      acc[ct] = __builtin_amdgcn_mfma_f32_16x16x32_bf16(a[ks], b, acc[ct], 0, 0, 0);
    }
  }
  int nbase = tile * 16;
  float degmask[4];
#pragma unroll
  for (int j = 0; j < 4; ++j)
    degmask[j] = (cnt[nbase + g * 4 + j] > 0) ? 1.0f : 0.0f;
#pragma unroll
  for (int ct = 0; ct < 8; ++ct) {
    int col = ct * 16 + r;
    float bi = b_in[col], bs = b_self[col];
    float s = 0.f, s2 = 0.f;
#pragma unroll
    for (int j = 0; j < 4; ++j) {
      float v = acc[ct][j] + bs + bi * degmask[j];
      xn[(size_t)(nbase + g * 4 + j) * DD + col] = v;
      s += v; s2 += v * v;
    }
    if (do_stats) {
      s += __shfl_xor(s, 16);  s += __shfl_xor(s, 32);
      s2 += __shfl_xor(s2, 16); s2 += __shfl_xor(s2, 32);
      if (g == 0) { atomicAdd(&gsum[col], s); atomicAdd(&gssq[col], s2); }
    }
  }
}

__global__ void k_bnfin(const float* __restrict__ gsum, const float* __restrict__ gssq,
    const float* __restrict__ gamma, const float* __restrict__ beta,
    float* __restrict__ scale, float* __restrict__ shift, int N) {
  int d = threadIdx.x;
  float mu = gsum[d] / (float)N;
  float var = gssq[d] / (float)N - mu * mu;
  float rs = rsqrtf(var + 1e-5f);
  float sc = rs * gamma[d];
  scale[d] = sc;
  shift[d] = beta[d] - mu * sc;
}

// reads f32 xn, applies BN affine + relu, writes bf16 xb
__global__ void k_bnrelu(const float* __restrict__ xin, u16* __restrict__ xout,
                         const float* __restrict__ scale,
                         const float* __restrict__ shift, int total4) {
  int i = blockIdx.x * blockDim.x + threadIdx.x;
  if (i >= total4) return;
  f32x4 v = ((const f32x4*)xin)[i];
  int d0 = (i * 4) & 127;
  bf16x4 o;
  o[0] = (short)f2bf(fmaxf(v.x * scale[d0]     + shift[d0],     0.f));
  o[1] = (short)f2bf(fmaxf(v.y * scale[d0 + 1] + shift[d0 + 1], 0.f));
  o[2] = (short)f2bf(fmaxf(v.z * scale[d0 + 2] + shift[d0 + 2], 0.f));
  o[3] = (short)f2bf(fmaxf(v.w * scale[d0 + 3] + shift[d0 + 3], 0.f));
  ((bf16x4*)xout)[i] = o;
}

static inline size_t alignup(size_t v, size_t a) { return (v + a - 1) & ~(a - 1); }

extern "C" void kernel_launch(void* const* d_in, const int* in_sizes, int n_in,
                              void* d_out, int out_size, void* d_ws, size_t ws_size,
                              hipStream_t stream) {
  const float* x0     = (const float*)d_in[0];
  const float* ea0    = (const float*)d_in[1];
  const float* w_self = (const float*)d_in[2];
  const float* b_self = (const float*)d_in[3];
  const float* w_in   = (const float*)d_in[4];
  const float* b_in   = (const float*)d_in[5];
  const float* w_rel  = (const float*)d_in[6];
  const float* b_rel  = (const float*)d_in[7];
  const float* gamma  = (const float*)d_in[8];
  const float* beta   = (const float*)d_in[9];
  const int*   idx    = (const int*)d_in[10];

  const int N = in_sizes[0] / DD;
  const int E = in_sizes[1] / DD;

  char* w = (char*)d_ws;
  size_t off = 0;
  int* cnt       = (int*)(w + off); off = alignup(off + (size_t)N * 4, 256);
  int* row_start = (int*)(w + off); off = alignup(off + (size_t)(N + 1) * 4, 256);
  int* cursor    = (int*)(w + off); off = alignup(off + (size_t)N * 4, 256);
  int* edge_of   = (int*)(w + off); off = alignup(off + (size_t)E * 4, 256);
  float* gsum    = (float*)(w + off); off = alignup(off + 128 * 4, 256);
  float* gssq    = (float*)(w + off); off = alignup(off + 128 * 4, 256);
  float* scale   = (float*)(w + off); off = alignup(off + 128 * 4, 256);
  float* shift   = (float*)(w + off); off = alignup(off + 128 * 4, 256);
  float* aggm    = (float*)(w + off); off = alignup(off + (size_t)N * DD * 4, 256);
  float* xn      = (float*)(w + off); off = alignup(off + (size_t)N * DD * 4, 256);
  u16*   xb      = (u16*)(w + off);   off = alignup(off + (size_t)N * DD * 2, 256);
  u16*   eaB     = (u16*)(w + off);   off = alignup(off + (size_t)E * DD * 2, 256);
  (void)ws_size; (void)n_in; (void)out_size;

  float* out_x  = (float*)d_out;
  float* out_ea = out_x + (size_t)N * DD;

  // ---- CSR build (depends only on edge_index) ----
  (void)hipMemsetAsync(cnt, 0, (size_t)N * 4, stream);
  int ethreads = 256, eblocks = (E + ethreads - 1) / ethreads;
  k_count<<<eblocks, ethreads, 0, stream>>>(idx, cnt, E);
  k_scan<<<1, 1024, 0, stream>>>(cnt, row_start, cursor, N);
  k_fill<<<eblocks, ethreads, 0, stream>>>(idx, cursor, edge_of, E);

  const int ntN = N / 16;           // 3125
  const int ntE = E / 16;           // 40000
  const int nodeBlocks = (ntN + 3) / 4;
  const int relBlocks = 2048;
  const int bnBlocks = ((size_t)N * DD / 4 + 255) / 256;

  // ---- layer 0 (f32 inputs -> bf16 intermediates) ----
  (void)hipMemsetAsync(gsum, 0, 128 * 4, stream);
  (void)hipMemsetAsync(gssq, 0, 128 * 4, stream);
  k_agg<float><<<N, 128, 0, stream>>>(x0, ea0, idx, row_start, edge_of, aggm);
  k_node<float><<<nodeBlocks, 256, 0, stream>>>(aggm, x0,
      w_in, w_self, b_in, b_self, cnt, xn, gsum, gssq, 1, ntN);
  k_rel<float, u16><<<relBlocks, 256, 0, stream>>>(ea0, eaB, w_rel, b_rel, ntE);
  k_bnfin<<<1, 128, 0, stream>>>(gsum, gssq, gamma, beta, scale, shift, N);
  k_bnrelu<<<bnBlocks, 256, 0, stream>>>(xn, xb, scale, shift, N * DD / 4);

  // ---- layer 1 (bf16 -> bf16) ----
  (void)hipMemsetAsync(gsum, 0, 128 * 4, stream);
  (void)hipMemsetAsync(gssq, 0, 128 * 4, stream);
  k_agg<u16><<<N, 128, 0, stream>>>(xb, eaB, idx, row_start, edge_of, aggm);
  k_node<u16><<<nodeBlocks, 256, 0, stream>>>(aggm, xb,
      w_in + DD * DD, w_self + DD * DD, b_in + DD, b_self + DD,
      cnt, xn, gsum, gssq, 1, ntN);
  k_rel<u16, u16><<<relBlocks, 256, 0, stream>>>(eaB, eaB,
      w_rel + DD * DD, b_rel + DD, ntE);        // in-place, per-row safe
  k_bnfin<<<1, 128, 0, stream>>>(gsum, gssq, gamma + DD, beta + DD, scale, shift, N);
  k_bnrelu<<<bnBlocks, 256, 0, stream>>>(xn, xb, scale, shift, N * DD / 4);

  // ---- layer 2 (bf16 -> f32 outputs) ----
  k_agg<u16><<<N, 128, 0, stream>>>(xb, eaB, idx, row_start, edge_of, aggm);
  k_node<u16><<<nodeBlocks, 256, 0, stream>>>(aggm, xb,
      w_in + 2 * DD * DD, w_self + 2 * DD * DD, b_in + 2 * DD, b_self + 2 * DD,
      cnt, out_x, gsum, gssq, 0, ntN);
  k_rel<u16, float><<<relBlocks, 256, 0, stream>>>(eaB, out_ea,
      w_rel + 2 * DD * DD, b_rel + 2 * DD, ntE);
}

// Round 5
// 1029.837 us; speedup vs baseline: 6.8742x; 1.1219x over previous
//
#include <hip/hip_runtime.h>

#define DD 128

typedef __attribute__((ext_vector_type(8))) short bf16x8;
typedef __attribute__((ext_vector_type(4))) short bf16x4;
typedef __attribute__((ext_vector_type(4))) float f32x4;
typedef unsigned short u16;

__device__ __forceinline__ unsigned short f2bf(float f) {
  union { float f; unsigned u; } v; v.f = f;
  unsigned u = v.u;
  return (unsigned short)((u + 0x7FFFu + ((u >> 16) & 1u)) >> 16);
}
__device__ __forceinline__ float bf2f(unsigned short h) {
  union { unsigned u; float f; } v; v.u = ((unsigned)h) << 16; return v.f;
}

__device__ __forceinline__ bf16x8 pack8(f32x4 a, f32x4 b) {
  bf16x8 r;
  r[0] = (short)f2bf(a.x); r[1] = (short)f2bf(a.y);
  r[2] = (short)f2bf(a.z); r[3] = (short)f2bf(a.w);
  r[4] = (short)f2bf(b.x); r[5] = (short)f2bf(b.y);
  r[6] = (short)f2bf(b.z); r[7] = (short)f2bf(b.w);
  return r;
}

// edge_index may arrive as int32 or int64. int64 viewed as int32 has zero
// high words at odd slots; values in [0,50000) make 4 zeros ~impossible.
__device__ __forceinline__ bool idx_is64(const int* p) {
  return (p[1] | p[3] | p[5] | p[7]) == 0;
}
__device__ __forceinline__ int ld_idx(const int* p, long long i, bool is64) {
  return is64 ? (int)((const long long*)p)[i] : p[i];
}

__global__ void k_count(const int* __restrict__ idx, int* __restrict__ cnt, int E) {
  int e = blockIdx.x * blockDim.x + threadIdx.x;
  if (e >= E) return;
  bool is64 = idx_is64(idx);
  int d = ld_idx(idx, (long long)E + e, is64);
  atomicAdd(&cnt[d], 1);
}

__global__ __launch_bounds__(1024) void k_scan(const int* __restrict__ cnt,
    int* __restrict__ row_start, int* __restrict__ cursor, int N) {
  __shared__ int part[1024];
  int t = threadIdx.x;
  int chunk = (N + 1023) >> 10;
  int lo = t * chunk, hi = lo + chunk; if (hi > N) hi = N; if (lo > N) lo = N;
  int s = 0;
  for (int i = lo; i < hi; ++i) s += cnt[i];
  part[t] = s;
  __syncthreads();
  for (int off = 1; off < 1024; off <<= 1) {
    int v = (t >= off) ? part[t - off] : 0;
    __syncthreads();
    part[t] += v;
    __syncthreads();
  }
  int run = (t == 0) ? 0 : part[t - 1];
  for (int i = lo; i < hi; ++i) {
    row_start[i] = run; cursor[i] = run; run += cnt[i];
  }
  if (t == 1023) row_start[N] = part[1023];
}

// CSR fill; also materializes src_csr so consumers never touch idx again.
__global__ void k_fill(const int* __restrict__ idx, int* __restrict__ cursor,
                       int* __restrict__ edge_of, int* __restrict__ src_csr, int E) {
  int e = blockIdx.x * blockDim.x + threadIdx.x;
  if (e >= E) return;
  bool is64 = idx_is64(idx);
  int s = ld_idx(idx, e, is64);
  int d = ld_idx(idx, (long long)E + e, is64);
  int pos = atomicAdd(&cursor[d], 1);
  edge_of[pos] = e;
  src_csr[pos] = s;
}

// Layer-0 aggregation: random-gathers f32 ea0/x0 (unavoidable, once),
// emits aggm (segment mean of x[src]*ea) and eaC = bf16(ea0) in CSR order.
// wave per node, 4 edges/iteration, lane = esub*16 + cg (8 channels each).
__global__ __launch_bounds__(256) void k_agg0(const float* __restrict__ x,
    const float* __restrict__ ea, const int* __restrict__ edge_of,
    const int* __restrict__ src_csr, const int* __restrict__ row_start,
    float* __restrict__ aggm, u16* __restrict__ eaC) {
  int n = blockIdx.x * 4 + (threadIdx.x >> 6);
  int lane = threadIdx.x & 63;
  int esub = lane >> 4, cg = lane & 15;
  int c0 = cg * 8;
  int s0 = row_start[n], s1 = row_start[n + 1];
  int len = s1 - s0;
  float acc[8];
#pragma unroll
  for (int j = 0; j < 8; ++j) acc[j] = 0.f;
  for (int kk = 0; kk < len; kk += 4) {
    int kx = kk + esub;
    bool act = kx < len;
    int k = s0 + (act ? kx : 0);
    int e = edge_of[k];
    int sn = src_csr[k];
    f32x4 e0 = *(const f32x4*)(ea + (size_t)e * DD + c0);
    f32x4 e1 = *(const f32x4*)(ea + (size_t)e * DD + c0 + 4);
    f32x4 x0 = *(const f32x4*)(x + (size_t)sn * DD + c0);
    f32x4 x1 = *(const f32x4*)(x + (size_t)sn * DD + c0 + 4);
    if (act) {
      *(bf16x8*)(eaC + (size_t)k * DD + c0) = pack8(e0, e1);
#pragma unroll
      for (int j = 0; j < 4; ++j) acc[j] += x0[j] * e0[j];
#pragma unroll
      for (int j = 0; j < 4; ++j) acc[4 + j] += x1[j] * e1[j];
    }
  }
  float inv = (len > 0) ? 1.0f / (float)len : 0.0f;
#pragma unroll
  for (int j = 0; j < 8; ++j) {
    float s = acc[j];
    s += __shfl_xor(s, 16);
    s += __shfl_xor(s, 32);
    acc[j] = s * inv;
  }
  if (esub == 0) {
    f32x4 lo, hi;
#pragma unroll
    for (int j = 0; j < 4; ++j) { lo[j] = acc[j]; hi[j] = acc[4 + j]; }
    *(f32x4*)(aggm + (size_t)n * DD + c0) = lo;
    *(f32x4*)(aggm + (size_t)n * DD + c0 + 4) = hi;
  }
}

// Layers 1/2 aggregation: eaC streamed sequentially (CSR order), x gathered
// via src_csr with BN affine+relu applied on load.
__global__ __launch_bounds__(256) void k_aggN(const u16* __restrict__ xb,
    const u16* __restrict__ eaC, const int* __restrict__ src_csr,
    const int* __restrict__ row_start, const float* __restrict__ scale,
    const float* __restrict__ shift, float* __restrict__ aggm) {
  int n = blockIdx.x * 4 + (threadIdx.x >> 6);
  int lane = threadIdx.x & 63;
  int esub = lane >> 4, cg = lane & 15;
  int c0 = cg * 8;
  float sc[8], sh[8];
#pragma unroll
  for (int j = 0; j < 8; ++j) { sc[j] = scale[c0 + j]; sh[j] = shift[c0 + j]; }
  int s0 = row_start[n], s1 = row_start[n + 1];
  int len = s1 - s0;
  float acc[8];
#pragma unroll
  for (int j = 0; j < 8; ++j) acc[j] = 0.f;
  for (int kk = 0; kk < len; kk += 4) {
    int kx = kk + esub;
    bool act = kx < len;
    int k = s0 + (act ? kx : 0);
    int sn = src_csr[k];
    bf16x8 ev = *(const bf16x8*)(eaC + (size_t)k * DD + c0);
    bf16x8 xv = *(const bf16x8*)(xb + (size_t)sn * DD + c0);
    if (act) {
#pragma unroll
      for (int j = 0; j < 8; ++j) {
        float xf = fmaxf(bf2f((u16)xv[j]) * sc[j] + sh[j], 0.f);
        acc[j] += xf * bf2f((u16)ev[j]);
      }
    }
  }
  float inv = (len > 0) ? 1.0f / (float)len : 0.0f;
#pragma unroll
  for (int j = 0; j < 8; ++j) {
    float s = acc[j];
    s += __shfl_xor(s, 16);
    s += __shfl_xor(s, 32);
    acc[j] = s * inv;
  }
  if (esub == 0) {
    f32x4 lo, hi;
#pragma unroll
    for (int j = 0; j < 4; ++j) { lo[j] = acc[j]; hi[j] = acc[4 + j]; }
    *(f32x4*)(aggm + (size_t)n * DD + c0) = lo;
    *(f32x4*)(aggm + (size_t)n * DD + c0 + 4) = hi;
  }
}

// Node update: xn = aggm @ W_in^T + BN?(x) @ W_self^T + b_self + (deg>0)*b_in
// TX: input x type; BN: apply scale/shift/relu to x on load; TO: output type
// (u16 => pre-BN bf16 intermediate); STATS: accumulate BN sum/ssq.
template <typename TX, bool BN, typename TO, bool STATS>
__global__ __launch_bounds__(256) void k_node(const float* __restrict__ aggm,
    const TX* __restrict__ xc, const float* __restrict__ W_in,
    const float* __restrict__ W_self, const float* __restrict__ b_in,
    const float* __restrict__ b_self, const int* __restrict__ row_start,
    const float* __restrict__ scale, const float* __restrict__ shift,
    TO* __restrict__ xn, float* __restrict__ gsum, float* __restrict__ gssq,
    int ntiles) {
  __shared__ short Wl[DD * 256];   // [f][k] k<128:W_in, k>=128:W_self (bf16, swizzled)
  for (int q = threadIdx.x; q < DD * 256 / 4; q += 256) {
    int off = q * 4;
    int f = off >> 8, k = off & 255;
    f32x4 w = (k < 128) ? *(const f32x4*)(W_in + f * 128 + k)
                        : *(const f32x4*)(W_self + f * 128 + (k - 128));
    unsigned byte = ((unsigned)(f * 512 + k * 2)) ^ (unsigned)((f & 7) << 4);
    bf16x4 s4;
    s4[0] = (short)f2bf(w.x); s4[1] = (short)f2bf(w.y);
    s4[2] = (short)f2bf(w.z); s4[3] = (short)f2bf(w.w);
    *(bf16x4*)((char*)Wl + byte) = s4;
  }
  __syncthreads();
  int wave = threadIdx.x >> 6, lane = threadIdx.x & 63;
  int tile = blockIdx.x * 4 + wave;
  if (tile >= ntiles) return;
  int r = lane & 15, g = lane >> 4;
  int arowi = tile * 16 + r;
  const float* arow = aggm + (size_t)arowi * DD;
  const TX* xrow = xc + (size_t)arowi * DD;
  bf16x8 a[8];
#pragma unroll
  for (int ks = 0; ks < 4; ++ks) {
    const float* p = arow + ks * 32 + g * 8;
    a[ks] = pack8(*(const f32x4*)p, *(const f32x4*)(p + 4));
  }
#pragma unroll
  for (int ks = 0; ks < 4; ++ks) {
    int c0 = ks * 32 + g * 8;
    float v[8];
    if constexpr (sizeof(TX) == 2) {
      bf16x8 raw = *(const bf16x8*)(xrow + c0);
#pragma unroll
      for (int j = 0; j < 8; ++j) v[j] = bf2f((u16)raw[j]);
    } else {
      f32x4 r0 = *(const f32x4*)((const float*)xrow + c0);
      f32x4 r1 = *(const f32x4*)((const float*)xrow + c0 + 4);
#pragma unroll
      for (int j = 0; j < 4; ++j) { v[j] = r0[j]; v[4 + j] = r1[j]; }
    }
    bf16x8 fr;
#pragma unroll
    for (int j = 0; j < 8; ++j) {
      float f = v[j];
      if constexpr (BN) f = fmaxf(f * scale[c0 + j] + shift[c0 + j], 0.f);
      fr[j] = (short)f2bf(f);
    }
    a[4 + ks] = fr;
  }
  f32x4 acc[8];
#pragma unroll
  for (int ct = 0; ct < 8; ++ct) acc[ct] = (f32x4){0.f, 0.f, 0.f, 0.f};
#pragma unroll
  for (int ct = 0; ct < 8; ++ct) {
    int f = ct * 16 + r;
    unsigned base = (unsigned)(f * 512);
    unsigned sw = (unsigned)((f & 7) << 4);
#pragma unroll
    for (int ks = 0; ks < 8; ++ks) {
      unsigned byte = (base + (unsigned)(ks * 64 + g * 16)) ^ sw;
      bf16x8 b = *(const bf16x8*)((const char*)Wl + byte);
      acc[ct] = __builtin_amdgcn_mfma_f32_16x16x32_bf16(a[ks], b, acc[ct], 0, 0, 0);
    }
  }
  int nbase = tile * 16;
  float degmask[4];
#pragma unroll
  for (int j = 0; j < 4; ++j) {
    int nn = nbase + g * 4 + j;
    degmask[j] = (row_start[nn + 1] > row_start[nn]) ? 1.0f : 0.0f;
  }
#pragma unroll
  for (int ct = 0; ct < 8; ++ct) {
    int col = ct * 16 + r;
    float bi = b_in[col], bs = b_self[col];
    float s = 0.f, s2 = 0.f;
#pragma unroll
    for (int j = 0; j < 4; ++j) {
      float v = acc[ct][j] + bs + bi * degmask[j];
      if constexpr (sizeof(TO) == 2) xn[(size_t)(nbase + g * 4 + j) * DD + col] = (TO)f2bf(v);
      else                            xn[(size_t)(nbase + g * 4 + j) * DD + col] = (TO)v;
      s += v; s2 += v * v;
    }
    if constexpr (STATS) {
      s += __shfl_xor(s, 16);  s += __shfl_xor(s, 32);
      s2 += __shfl_xor(s2, 16); s2 += __shfl_xor(s2, 32);
      if (g == 0) { atomicAdd(&gsum[col], s); atomicAdd(&gssq[col], s2); }
    }
  }
}

// ea GEMM on CSR-ordered buffer. SCATTER=false: in-place sequential bf16.
// SCATTER=true: write f32 rows to out[edge_of[k]] (restore original order).
template <bool SCATTER, typename TO>
__global__ __launch_bounds__(256) void k_rel(const u16* __restrict__ ea_in,
    TO* __restrict__ ea_out, const int* __restrict__ edge_of,
    const float* __restrict__ W, const float* __restrict__ bias, int ntiles) {
  __shared__ short Wl[DD * DD];
  for (int q = threadIdx.x; q < DD * DD / 4; q += 256) {
    int off = q * 4;
    int f = off >> 7, d = off & 127;
    f32x4 w = *(const f32x4*)(W + off);
    unsigned byte = ((unsigned)(f * 256 + d * 2)) ^ (unsigned)((f & 7) << 4);
    bf16x4 s4;
    s4[0] = (short)f2bf(w.x); s4[1] = (short)f2bf(w.y);
    s4[2] = (short)f2bf(w.z); s4[3] = (short)f2bf(w.w);
    *(bf16x4*)((char*)Wl + byte) = s4;
  }
  __syncthreads();
  int wave = threadIdx.x >> 6, lane = threadIdx.x & 63;
  int r = lane & 15, g = lane >> 4;
  for (int tile = blockIdx.x * 4 + wave; tile < ntiles; tile += gridDim.x * 4) {
    const u16* rowp = ea_in + (size_t)(tile * 16 + r) * DD;
    bf16x8 a[4];
#pragma unroll
    for (int ks = 0; ks < 4; ++ks) a[ks] = *(const bf16x8*)(rowp + ks * 32 + g * 8);
    f32x4 acc[8];
#pragma unroll
    for (int ct = 0; ct < 8; ++ct) acc[ct] = (f32x4){0.f, 0.f, 0.f, 0.f};
#pragma unroll
    for (int ct = 0; ct < 8; ++ct) {
      int f = ct * 16 + r;
      unsigned base = (unsigned)(f * 256);
      unsigned sw = (unsigned)((f & 7) << 4);
#pragma unroll
      for (int ks = 0; ks < 4; ++ks) {
        unsigned byte = (base + (unsigned)(ks * 64 + g * 16)) ^ sw;
        bf16x8 b = *(const bf16x8*)((const char*)Wl + byte);
        acc[ct] = __builtin_amdgcn_mfma_f32_16x16x32_bf16(a[ks], b, acc[ct], 0, 0, 0);
      }
    }
    size_t orow[4];
#pragma unroll
    for (int j = 0; j < 4; ++j) {
      int kr = tile * 16 + g * 4 + j;
      orow[j] = SCATTER ? (size_t)edge_of[kr] : (size_t)kr;
    }
#pragma unroll
    for (int ct = 0; ct < 8; ++ct) {
      int col = ct * 16 + r;
      float bv = bias[col];
#pragma unroll
      for (int j = 0; j < 4; ++j) {
        float v = acc[ct][j] + bv;
        if constexpr (sizeof(TO) == 2) ea_out[orow[j] * DD + col] = (TO)f2bf(v);
        else                            ea_out[orow[j] * DD + col] = (TO)v;
      }
    }
  }
}

__global__ void k_bnfin(const float* __restrict__ gsum, const float* __restrict__ gssq,
    const float* __restrict__ gamma, const float* __restrict__ beta,
    float* __restrict__ scale, float* __restrict__ shift, int N) {
  int d = threadIdx.x;
  float mu = gsum[d] / (float)N;
  float var = gssq[d] / (float)N - mu * mu;
  float rs = rsqrtf(var + 1e-5f);
  float sc = rs * gamma[d];
  scale[d] = sc;
  shift[d] = beta[d] - mu * sc;
}

static inline size_t alignup(size_t v, size_t a) { return (v + a - 1) & ~(a - 1); }

extern "C" void kernel_launch(void* const* d_in, const int* in_sizes, int n_in,
                              void* d_out, int out_size, void* d_ws, size_t ws_size,
                              hipStream_t stream) {
  const float* x0     = (const float*)d_in[0];
  const float* ea0    = (const float*)d_in[1];
  const float* w_self = (const float*)d_in[2];
  const float* b_self = (const float*)d_in[3];
  const float* w_in   = (const float*)d_in[4];
  const float* b_in   = (const float*)d_in[5];
  const float* w_rel  = (const float*)d_in[6];
  const float* b_rel  = (const float*)d_in[7];
  const float* gamma  = (const float*)d_in[8];
  const float* beta   = (const float*)d_in[9];
  const int*   idx    = (const int*)d_in[10];

  const int N = in_sizes[0] / DD;
  const int E = in_sizes[1] / DD;

  char* w = (char*)d_ws;
  size_t off = 0;
  int* cnt       = (int*)(w + off); off = alignup(off + (size_t)N * 4, 256);
  int* row_start = (int*)(w + off); off = alignup(off + (size_t)(N + 1) * 4, 256);
  int* cursor    = (int*)(w + off); off = alignup(off + (size_t)N * 4, 256);
  int* edge_of   = (int*)(w + off); off = alignup(off + (size_t)E * 4, 256);
  int* src_csr   = (int*)(w + off); off = alignup(off + (size_t)E * 4, 256);
  float* gstats  = (float*)(w + off); off = alignup(off + 256 * 4, 256);
  float* scale   = (float*)(w + off); off = alignup(off + 128 * 4, 256);
  float* shift   = (float*)(w + off); off = alignup(off + 128 * 4, 256);
  float* aggm    = (float*)(w + off); off = alignup(off + (size_t)N * DD * 4, 256);
  u16*   xb      = (u16*)(w + off);   off = alignup(off + (size_t)N * DD * 2, 256);
  u16*   eaC     = (u16*)(w + off);   off = alignup(off + (size_t)E * DD * 2, 256);
  float* gsum = gstats, *gssq = gstats + 128;
  (void)ws_size; (void)n_in; (void)out_size;

  float* out_x  = (float*)d_out;
  float* out_ea = out_x + (size_t)N * DD;

  // ---- CSR build ----
  (void)hipMemsetAsync(cnt, 0, (size_t)N * 4, stream);
  int ethreads = 256, eblocks = (E + ethreads - 1) / ethreads;
  k_count<<<eblocks, ethreads, 0, stream>>>(idx, cnt, E);
  k_scan<<<1, 1024, 0, stream>>>(cnt, row_start, cursor, N);
  k_fill<<<eblocks, ethreads, 0, stream>>>(idx, cursor, edge_of, src_csr, E);

  const int ntN = N / 16;                 // 3125
  const int ntE = E / 16;                 // 40000
  const int aggBlocks = (N + 3) / 4;      // wave per node
  const int nodeBlocks = (ntN + 3) / 4;
  const int relBlocks = 2048;

  // ---- layer 0 ----
  (void)hipMemsetAsync(gstats, 0, 256 * 4, stream);
  k_agg0<<<aggBlocks, 256, 0, stream>>>(x0, ea0, edge_of, src_csr, row_start,
                                        aggm, eaC);
  k_node<float, false, u16, true><<<nodeBlocks, 256, 0, stream>>>(aggm, x0,
      w_in, w_self, b_in, b_self, row_start, scale, shift,
      xb, gsum, gssq, ntN);
  k_rel<false, u16><<<relBlocks, 256, 0, stream>>>(eaC, eaC, edge_of,
      w_rel, b_rel, ntE);
  k_bnfin<<<1, 128, 0, stream>>>(gsum, gssq, gamma, beta, scale, shift, N);

  // ---- layer 1 ----
  (void)hipMemsetAsync(gstats, 0, 256 * 4, stream);
  k_aggN<<<aggBlocks, 256, 0, stream>>>(xb, eaC, src_csr, row_start,
                                        scale, shift, aggm);
  k_node<u16, true, u16, true><<<nodeBlocks, 256, 0, stream>>>(aggm, xb,
      w_in + DD * DD, w_self + DD * DD, b_in + DD, b_self + DD,
      row_start, scale, shift, xb, gsum, gssq, ntN);
  k_rel<false, u16><<<relBlocks, 256, 0, stream>>>(eaC, eaC, edge_of,
      w_rel + DD * DD, b_rel + DD, ntE);
  k_bnfin<<<1, 128, 0, stream>>>(gsum, gssq, gamma + DD, beta + DD, scale, shift, N);

  // ---- layer 2 ----
  k_aggN<<<aggBlocks, 256, 0, stream>>>(xb, eaC, src_csr, row_start,
                                        scale, shift, aggm);
  k_node<u16, true, float, false><<<nodeBlocks, 256, 0, stream>>>(aggm, xb,
      w_in + 2 * DD * DD, w_self + 2 * DD * DD, b_in + 2 * DD, b_self + 2 * DD,
      row_start, scale, shift, out_x, gsum, gssq, ntN);
  k_rel<true, float><<<relBlocks, 256, 0, stream>>>(eaC, out_ea, edge_of,
      w_rel + 2 * DD * DD, b_rel + 2 * DD, ntE);
}